// Round 17
// baseline (99.255 us; speedup 1.0000x reference)
//
#include <hip/hip_runtime.h>
#include <hip/hip_bf16.h>
#include <math.h>

// ---------------- problem constants ----------------
#define N_ROWS 8192
#define DIM    512
#define NCLS   64
#define BMR    256   // tile rows (4 wave-bands of 64)
#define BNC    128   // tile cols (2 wave-strips of 64)
#define BK     64    // K step
#define NKT    (DIM / BK)                    // 8 K-tiles
#define NRT    (N_ROWS / BMR)                // 32 row-tiles
#define NCT    (N_ROWS / BNC)                // 64 col-tiles
#define NBLK   1056                          // sum_{i<32}(64-2i) = 8 * 132
#define NSLOT  (NCT + NRT)                   // 96 partial slots (64 row-path + 32 col-path)
#define M_CONST 14.285714285714286f          // 1/T : the fixed max-shift (diagonal)
#define L2E     1.4426950408889634f          // log2(e)
#define M2_CONST 20.60992915555662f          // log2(e)/T (shift in exp2 units)
#define SCALE2  4.539815541256959f           // sqrt(log2(e)/T): MFMA outputs log2e*sim

using bf16x8 = __attribute__((ext_vector_type(8))) short;
using f32x4  = __attribute__((ext_vector_type(4))) float;

static __device__ inline unsigned short f2bf(float x) {
  unsigned u = __float_as_uint(x);
  unsigned r = u + 0x7FFFu + ((u >> 16) & 1u);   // RNE
  return (unsigned short)(r >> 16);
}

// ---- kernel 1: L2-normalize rows, scale by sqrt(log2e/T), cast bf16 -----------
__global__ __launch_bounds__(256) void normalize_rows(const float* __restrict__ proj,
                                                      unsigned short* __restrict__ outb) {
  const int row  = blockIdx.x * 4 + (threadIdx.x >> 6);
  const int lane = threadIdx.x & 63;
  const float4* src = (const float4*)(proj + (size_t)row * DIM);
  float4 a = src[lane * 2];
  float4 b = src[lane * 2 + 1];
  float ss = a.x*a.x + a.y*a.y + a.z*a.z + a.w*a.w
           + b.x*b.x + b.y*b.y + b.z*b.z + b.w*b.w;
#pragma unroll
  for (int off = 1; off < 64; off <<= 1) ss += __shfl_xor(ss, off);
  const float scale = SCALE2 / fmaxf(sqrtf(ss), 1e-12f);
  float v[8] = {a.x, a.y, a.z, a.w, b.x, b.y, b.z, b.w};
  unsigned short h[8];
#pragma unroll
  for (int i = 0; i < 8; ++i) h[i] = f2bf(v[i] * scale);
  uint4 packed;
  packed.x = (unsigned)h[0] | ((unsigned)h[1] << 16);
  packed.y = (unsigned)h[2] | ((unsigned)h[3] << 16);
  packed.z = (unsigned)h[4] | ((unsigned)h[5] << 16);
  packed.w = (unsigned)h[6] | ((unsigned)h[7] << 16);
  *(uint4*)(outb + (size_t)row * DIM + lane * 8) = packed;
}

// ---- kernel 2: 256x128 rectangular tile, 8 waves of 64x64, spill-free ---------
// Budget identity: 512 thr + 96KB LDS -> 1 blk/CU -> 2 waves/SIMD -> 256
// regs/wave (unified). acc = 64 AGPR (wave-tile 64x64) -> arch headroom 192
// >> demand ~100 -> NO spill (R14-16 failed: 16-wave blocks split 64+64;
// R10/11 failed: acc-128 left arch 128 < 146). LDS-read ratio matches R16
// (16 b128 / 32 MFMA / wave-K-tile). Strict-upper per-element masking
// (col>row) covers each off-diagonal pair exactly once; no diag special
// case. Row-path -> slot j; col-path -> slot 64+i; dpart/spart pre-zeroed.
// Schedule: R9's counted-vmcnt body, vmcnt(6) = this thread's 6 tile loads.
__global__ __launch_bounds__(512) void supcon_tile(const unsigned short* __restrict__ p16,
                                                   const int* __restrict__ tgt,
                                                   float* __restrict__ dpart,
                                                   float* __restrict__ spart) {
  // XCD-chunked bijective remap (1056 = 8*132), then rect-triangle decode
  const int logical = ((int)blockIdx.x & 7) * (NBLK / 8) + ((int)blockIdx.x >> 3);
  int rem = logical, bi = 0;
  while (rem >= NCT - 2 * bi) { rem -= NCT - 2 * bi; ++bi; }
  const int bj = 2 * bi + rem;                 // col-tile, bj >= 2*bi

  __shared__ short As[2][BMR * BK];   // 2 x 32 KB
  __shared__ short Bs[2][BNC * BK];   // 2 x 16 KB
  __shared__ int   tgr[BMR], tgc[BNC];
  __shared__ float redE[2][BMR], redS[2][BMR];   // row partials per wn
  __shared__ float redEc[4][BNC], redSc[4][BNC]; // col partials per wm

  const int tid  = threadIdx.x;
  const int lane = tid & 63;
  const int wid  = tid >> 6;          // 0..7
  const int wm = wid >> 1, wn = wid & 1;          // 4 row-bands x 2 col-strips
  const int lhi = lane >> 4, llo = lane & 15;
  const int swz = llo & 7;

  const size_t rowA0 = (size_t)bi * BMR;          // global row base
  const size_t colB0 = (size_t)bj * BNC;          // global col base

  // fragment-read bases: swizzle key (row&7) == (llo&7), uniform over mi/ni
  const int aoff = (wm * 64 + llo) * BK;
  const int boff = (wn * 64 + llo) * BK;
  const int kc0  = (lhi ^ swz) * 8;
  const int kc1  = ((4 + lhi) ^ swz) * 8;

  // staging: A = 2048 granules (4/thread), B = 1024 (2/thread); 6 loads total.
  // LDS dest linear in g; global source granule pre-swizzled (key r&7).
#define STAGE(BUF, KT) do {                                                         \
  _Pragma("unroll")                                                                 \
  for (int j = 0; j < 4; ++j) {                                                     \
    const int g  = tid + j * 512;                                                   \
    const int r  = g >> 3, gp = g & 7;                                              \
    const int gl = gp ^ (r & 7);                                                    \
    const unsigned short* sA = p16 + (rowA0 + r) * DIM + (KT) * BK + gl * 8;        \
    __builtin_amdgcn_global_load_lds((const __attribute__((address_space(1))) void*)sA, \
        (__attribute__((address_space(3))) void*)&As[BUF][g * 8], 16, 0, 0);        \
  }                                                                                 \
  _Pragma("unroll")                                                                 \
  for (int j = 0; j < 2; ++j) {                                                     \
    const int g  = tid + j * 512;                                                   \
    const int r  = g >> 3, gp = g & 7;                                              \
    const int gl = gp ^ (r & 7);                                                    \
    const unsigned short* sB = p16 + (colB0 + r) * DIM + (KT) * BK + gl * 8;        \
    __builtin_amdgcn_global_load_lds((const __attribute__((address_space(1))) void*)sB, \
        (__attribute__((address_space(3))) void*)&Bs[BUF][g * 8], 16, 0, 0);        \
  }                                                                                 \
} while (0)

  STAGE(0, 0);
  if (tid < BMR)                 tgr[tid] = tgt[rowA0 + tid];
  else if (tid < BMR + BNC)      tgc[tid - BMR] = tgt[colB0 + (tid - BMR)];

  f32x4 zero = {0.f, 0.f, 0.f, 0.f};
  f32x4 acc[4][4];
#pragma unroll
  for (int i = 0; i < 4; ++i)
#pragma unroll
    for (int j = 0; j < 4; ++j) acc[i][j] = zero;

  __syncthreads();   // prologue drain; buf0 + targets ready

#pragma unroll
  for (int kt = 0; kt < NKT; ++kt) {
    const int cur = kt & 1, nxt = cur ^ 1;

    if (kt > 0) {
      __builtin_amdgcn_s_barrier();     // buf[nxt] reads (tile kt-1) done
      __builtin_amdgcn_sched_barrier(0);
    }
    if (kt + 1 < NKT) {
      STAGE(nxt, kt + 1);                              // 6 loads stay in flight
      asm volatile("s_waitcnt vmcnt(6)" ::: "memory"); // waits ONLY tile kt's
    } else {
      asm volatile("s_waitcnt vmcnt(0)" ::: "memory");
    }
    __builtin_amdgcn_sched_barrier(0);
    __builtin_amdgcn_s_barrier();                      // loads(kt) landed
    __builtin_amdgcn_sched_barrier(0);

    const short* As_c = &As[cur][aoff];
    const short* Bs_c = &Bs[cur][boff];
#pragma unroll
    for (int ks = 0; ks < 2; ++ks) {
      const int kc = ks ? kc1 : kc0;
      bf16x8 af[4], bfr[4];
#pragma unroll
      for (int mi = 0; mi < 4; ++mi)
        af[mi] = *(const bf16x8*)(As_c + kc + mi * (16 * BK));
#pragma unroll
      for (int ni = 0; ni < 4; ++ni)
        bfr[ni] = *(const bf16x8*)(Bs_c + kc + ni * (16 * BK));
#pragma unroll
      for (int mi = 0; mi < 4; ++mi)
#pragma unroll
        for (int ni = 0; ni < 4; ++ni)
          acc[mi][ni] = __builtin_amdgcn_mfma_f32_16x16x32_bf16(af[mi], bfr[ni], acc[mi][ni], 0, 0, 0);
    }
  }
#undef STAGE

  // ---- epilogue: strict-upper masking (global col > global row) --------------
  int tc[4];
#pragma unroll
  for (int ni = 0; ni < 4; ++ni) tc[ni] = tgc[wn * 64 + ni * 16 + llo];
  float ecol[4] = {0.f, 0.f, 0.f, 0.f};
  float scol[4] = {0.f, 0.f, 0.f, 0.f};

#pragma unroll
  for (int mi = 0; mi < 4; ++mi) {
#pragma unroll
    for (int rg = 0; rg < 4; ++rg) {
      const int rin  = wm * 64 + mi * 16 + lhi * 4 + rg;    // row within tile
      const int rg_g = (int)rowA0 + rin;                    // global row
      const int trow = tgr[rin];
      float esum = 0.f, ssum = 0.f;
#pragma unroll
      for (int ni = 0; ni < 4; ++ni) {
        const int cin  = wn * 64 + ni * 16 + llo;           // col within tile
        const int cg_g = (int)colB0 + cin;                  // global col
        const float x = acc[mi][ni][rg];                    // log2e * sim
        const bool valid = cg_g > rg_g;                     // strict upper
        const float e = valid ? __builtin_amdgcn_exp2f(x - M2_CONST) : 0.f;
        const bool pos = valid && (trow == tc[ni]);
        const float sv = pos ? x : 0.f;
        esum += e;  ssum += sv;
        ecol[ni] += e;  scol[ni] += sv;
      }
#pragma unroll
      for (int off = 1; off < 16; off <<= 1) {
        esum += __shfl_xor(esum, off);
        ssum += __shfl_xor(ssum, off);
      }
      if (llo == 0) { redE[wn][rin] = esum; redS[wn][rin] = ssum; }
    }
  }
  // col sums (transpose contributions)
#pragma unroll
  for (int ni = 0; ni < 4; ++ni) {
    float ec = ecol[ni], sc = scol[ni];
    ec += __shfl_xor(ec, 16); ec += __shfl_xor(ec, 32);
    sc += __shfl_xor(sc, 16); sc += __shfl_xor(sc, 32);
    if (lhi == 0) {
      redEc[wm][wn * 64 + ni * 16 + llo] = ec;
      redSc[wm][wn * 64 + ni * 16 + llo] = sc;
    }
  }
  __syncthreads();

  // writes: row-path under slot bj (rows disjoint across bi); col-path under
  // slot 64+bi (cols disjoint across bj). dpart/spart pre-zeroed by memset.
  if (tid < BMR) {
    dpart[(size_t)bj * N_ROWS + rowA0 + tid] = redE[0][tid] + redE[1][tid];
    spart[(size_t)bj * N_ROWS + rowA0 + tid] = redS[0][tid] + redS[1][tid];
  } else if (tid < BMR + BNC) {
    const int c = tid - BMR;
    dpart[(size_t)(NCT + bi) * N_ROWS + colB0 + c] =
        redEc[0][c] + redEc[1][c] + redEc[2][c] + redEc[3][c];
    spart[(size_t)(NCT + bi) * N_ROWS + colB0 + c] =
        redSc[0][c] + redSc[1][c] + redSc[2][c] + redSc[3][c];
  }
}

// ---- kernel 3: combine partials -> per-sample loss (hist inlined) -------------
__global__ __launch_bounds__(256) void combine_loss(const float* __restrict__ dpart,
                                                    const float* __restrict__ spart,
                                                    const int* __restrict__ tgt,
                                                    float* __restrict__ out) {
  __shared__ float dsh[4][64], ssh[4][64];
  __shared__ int   hloc[NCLS];
  const int tid  = threadIdx.x;
  const int lane = tid & 63;
  const int g    = tid >> 6;
  const int r    = blockIdx.x * 64 + lane;

  if (tid < NCLS) hloc[tid] = 0;
  __syncthreads();
  for (int i = tid; i < N_ROWS; i += 256) atomicAdd(&hloc[tgt[i]], 1);

  float d = 0.f, s = 0.f;
  for (int k = g * (NSLOT / 4); k < (g + 1) * (NSLOT / 4); ++k) {
    d += dpart[(size_t)k * N_ROWS + r];
    s += spart[(size_t)k * N_ROWS + r];
  }
  dsh[g][lane] = d; ssh[g][lane] = s;
  __syncthreads();
  if (g == 0) {
    d = dsh[0][lane] + dsh[1][lane] + dsh[2][lane] + dsh[3][lane];
    s = ssh[0][lane] + ssh[1][lane] + ssh[2][lane] + ssh[3][lane];
    const int cnt = hloc[tgt[r]] - 1;
    // s is in log2e*sim units -> divide back by L2E
    out[r] = (cnt > 0) ? (s / (L2E * (float)cnt) - M_CONST - logf(d + 1e-8f)) : 0.f;
  }
}

// ---------------- launcher ----------------
extern "C" void kernel_launch(void* const* d_in, const int* in_sizes, int n_in,
                              void* d_out, int out_size, void* d_ws, size_t ws_size,
                              hipStream_t stream) {
  const float* proj = (const float*)d_in[0];
  const int*   tgt  = (const int*)d_in[1];
  float* out = (float*)d_out;

  char* ws = (char*)d_ws;
  unsigned short* p16  = (unsigned short*)ws;                        // 8 MB
  float* dpart = (float*)(ws + (size_t)8 * 1024 * 1024);             // 3 MB (96 x 8192)
  float* spart = (float*)(ws + (size_t)11 * 1024 * 1024);            // 3 MB

  // zero partials (coverage holes in the rect-triangle slot scheme read as 0)
  (void)hipMemsetAsync(dpart, 0, (size_t)2 * NSLOT * N_ROWS * sizeof(float), stream);
  normalize_rows<<<N_ROWS / 4, 256, 0, stream>>>(proj, p16);
  supcon_tile<<<NBLK, 512, 0, stream>>>(p16, tgt, dpart, spart);
  combine_loss<<<N_ROWS / 64, 256, 0, stream>>>(dpart, spart, tgt, out);
}